// Round 2
// baseline (231.766 us; speedup 1.0000x reference)
//
#include <hip/hip_runtime.h>
#include <math.h>

#define RAD2DEG 57.29577951308232f

constexpr int S1_BLOCKS = 2048;
constexpr int S1_TPB    = 256;
constexpr int NPAIR     = 4;     // pairs per thread in the batched fast path

// Absolute angular distance in degrees between vectors (ax,ay) and (bx,by).
// == wrap(atan2(ay,ax)*RAD2DEG - atan2(by,bx)*RAD2DEG) from the reference.
__device__ __forceinline__ float angdist_deg(float ax, float ay,
                                             float bx, float by) {
    float dot = ax * bx + ay * by;
    float cr  = fabsf(ay * bx - ax * by);
    float ad  = fabsf(dot);
    float mn  = fminf(cr, ad);
    float mx  = fmaxf(cr, ad);
    float t   = mn * __builtin_amdgcn_rcpf(fmaxf(mx, 1e-37f));
    float s   = t * t;
    // minimax poly for atan(t), t in [0,1]; max err ~2.3e-5 rad (~0.0013 deg)
    float p = fmaf(s, -0.01172120f, 0.05265332f);
    p = fmaf(s, p, -0.11643287f);
    p = fmaf(s, p,  0.19354346f);
    p = fmaf(s, p, -0.33262347f);
    p = fmaf(s, p,  0.99997726f);
    float a = t * p;                                   // [0, pi/4]
    a = (cr > ad)    ? (1.57079632679489662f - a) : a; // [0, pi/2]
    a = (dot < 0.0f) ? (3.14159265358979323f - a) : a; // [0, pi]
    return a * RAD2DEG;
}

__device__ __forceinline__ void per_row(
    float l1x, float l2x, float l1y, float l2y, float l1z, float l2z,
    float e1x, float e1y, float e1z, float e2x, float e2y, float e2z,
    int mw,
    float& sS, float& sM, float& sC0, float& sM1, float& sM2)
{
    float dx, dy, dz;
    dx = e1x - l1x; dy = e1y - l1y; dz = e1z - l1z;
    float d11 = dx*dx + dy*dy + dz*dz;
    dx = e2x - l2x; dy = e2y - l2y; dz = e2z - l2z;
    float d22 = dx*dx + dy*dy + dz*dz;
    dx = e2x - l1x; dy = e2y - l1y; dz = e2z - l1z;
    float d21 = dx*dx + dy*dy + dz*dz;
    dx = e1x - l2x; dy = e1y - l2y; dz = e1z - l2z;
    float d12 = dx*dx + dy*dy + dz*dz;

    sS += d11;

    float mixed = fminf(d11 + d22, d21 + d12) * (1.0f / 3.0f);
    float m = (mw != 0) ? 1.0f : 0.0f;
    sM  += m * mixed;
    sC0 += 1.0f - m;

    float e11 = angdist_deg(l1x, l1y, e1x, e1y);
    float e22 = angdist_deg(l2x, l2y, e2x, e2y);
    float e12 = angdist_deg(l1x, l1y, e2x, e2y);
    float e21 = angdist_deg(l2x, l2y, e1x, e1y);

    bool ud = (e11 + e22) < (e12 + e21);
    sM1 += ud ? e11 : e12;
    sM2 += ud ? e22 : e21;
}

__device__ __forceinline__ void per_pair(
    const float4& L0, const float4& L1, const float4& L2,
    const float4& E0, const float4& E1, const float4& E2,
    const int2& mw,
    float& sS, float& sM, float& sC0, float& sM1, float& sM2)
{
    per_row(L0.x, L0.y, L0.z, L0.w, L1.x, L1.y,
            E0.x, E0.y, E0.z, E0.w, E1.x, E1.y,
            mw.x, sS, sM, sC0, sM1, sM2);
    per_row(L1.z, L1.w, L2.x, L2.y, L2.z, L2.w,
            E1.z, E1.w, E2.x, E2.y, E2.z, E2.w,
            mw.y, sS, sM, sC0, sM1, sM2);
}

// Latency-concurrency design: each thread owns NPAIR=4 pairs (grid-strided),
// issues ALL 26 independent loads (24x dwordx4 + 2x... int2 pairs grouped as
// 4x dwordx2) up-front -> ~26 KB in flight per wave before the first use.
// No LDS, no barriers in the hot path. In-flight bytes per CU during the
// load phase ~= resident_waves * 26 KB >> 9 KB needed to saturate HBM.
__global__ __launch_bounds__(S1_TPB) void stage1_kernel(
    const float* __restrict__ label,
    const float* __restrict__ est,
    const int*   __restrict__ mix,
    float* __restrict__ partials,   // [gridDim.x][5]
    int P)                          // number of row-pairs = B/2
{
    const int tid   = threadIdx.x;
    const int wid   = tid >> 6;
    const int lane  = tid & 63;
    const int gsize = gridDim.x * S1_TPB;
    const int g     = blockIdx.x * S1_TPB + tid;

    const float4* lab4 = (const float4*)label;
    const float4* est4 = (const float4*)est;
    const int2*   mix2 = (const int2*)mix;

    float sS = 0.f, sM = 0.f, sC0 = 0.f, sM1 = 0.f, sM2 = 0.f;

    int p = g;
    // fast path: NPAIR strided pairs per thread, all loads issued before any use
    for (; p + (NPAIR - 1) * gsize < P; p += NPAIR * gsize) {
        float4 Lv[NPAIR][3];
        float4 Ev[NPAIR][3];
        int2   Mv[NPAIR];
        #pragma unroll
        for (int k = 0; k < NPAIR; ++k) {
            const float4* lp = lab4 + (size_t)(p + k * gsize) * 3;
            Lv[k][0] = lp[0]; Lv[k][1] = lp[1]; Lv[k][2] = lp[2];
        }
        #pragma unroll
        for (int k = 0; k < NPAIR; ++k) {
            const float4* ep = est4 + (size_t)(p + k * gsize) * 3;
            Ev[k][0] = ep[0]; Ev[k][1] = ep[1]; Ev[k][2] = ep[2];
        }
        #pragma unroll
        for (int k = 0; k < NPAIR; ++k) {
            Mv[k] = mix2[p + k * gsize];
        }
        #pragma unroll
        for (int k = 0; k < NPAIR; ++k) {
            per_pair(Lv[k][0], Lv[k][1], Lv[k][2],
                     Ev[k][0], Ev[k][1], Ev[k][2],
                     Mv[k], sS, sM, sC0, sM1, sM2);
        }
    }
    // tail: one pair at a time
    for (; p < P; p += gsize) {
        const float4* lp = lab4 + (size_t)p * 3;
        const float4* ep = est4 + (size_t)p * 3;
        float4 L0 = lp[0], L1 = lp[1], L2 = lp[2];
        float4 E0 = ep[0], E1 = ep[1], E2 = ep[2];
        int2 mw = mix2[p];
        per_pair(L0, L1, L2, E0, E1, E2, mw, sS, sM, sC0, sM1, sM2);
    }

    // wave (64-lane) shuffle reduction
    for (int off = 32; off > 0; off >>= 1) {
        sS  += __shfl_down(sS,  off, 64);
        sM  += __shfl_down(sM,  off, 64);
        sC0 += __shfl_down(sC0, off, 64);
        sM1 += __shfl_down(sM1, off, 64);
        sM2 += __shfl_down(sM2, off, 64);
    }

    __shared__ float red[S1_TPB / 64][5];
    if (lane == 0) {
        red[wid][0] = sS; red[wid][1] = sM; red[wid][2] = sC0;
        red[wid][3] = sM1; red[wid][4] = sM2;
    }
    __syncthreads();
    if (tid == 0) {
        float r0 = 0.f, r1 = 0.f, r2 = 0.f, r3 = 0.f, r4 = 0.f;
        #pragma unroll
        for (int w = 0; w < S1_TPB / 64; ++w) {
            r0 += red[w][0]; r1 += red[w][1]; r2 += red[w][2];
            r3 += red[w][3]; r4 += red[w][4];
        }
        float* out = partials + (size_t)blockIdx.x * 5;
        out[0] = r0; out[1] = r1; out[2] = r2; out[3] = r3; out[4] = r4;
    }
}

__global__ __launch_bounds__(256) void stage2_kernel(
    const float* __restrict__ partials,
    float* __restrict__ out,
    int nblocks,
    long long Btot)
{
    const int tid = threadIdx.x;
    double aS = 0, aM = 0, aC0 = 0, aM1 = 0, aM2 = 0;
    for (int r = tid; r < nblocks; r += 256) {
        const float* row = partials + (size_t)r * 5;
        aS += row[0]; aM += row[1]; aC0 += row[2]; aM1 += row[3]; aM2 += row[4];
    }
    for (int off = 32; off > 0; off >>= 1) {
        aS  += __shfl_down(aS,  off, 64);
        aM  += __shfl_down(aM,  off, 64);
        aC0 += __shfl_down(aC0, off, 64);
        aM1 += __shfl_down(aM1, off, 64);
        aM2 += __shfl_down(aM2, off, 64);
    }
    __shared__ double red[4][5];
    const int wid = tid >> 6, lane = tid & 63;
    if (lane == 0) {
        red[wid][0] = aS; red[wid][1] = aM; red[wid][2] = aC0;
        red[wid][3] = aM1; red[wid][4] = aM2;
    }
    __syncthreads();
    if (tid == 0) {
        double S = 0, M = 0, C0 = 0, M1 = 0, M2 = 0;
        #pragma unroll
        for (int w = 0; w < 4; ++w) {
            S += red[w][0]; M += red[w][1]; C0 += red[w][2];
            M1 += red[w][3]; M2 += red[w][4];
        }
        const double Bd = (double)Btot;
        const double single_loss = S / (3.0 * Bd);
        out[0] = (float)((C0 * single_loss + M) / Bd);
        out[1] = (float)(M1 / Bd);
        out[2] = (float)(M2 / Bd);
    }
}

extern "C" void kernel_launch(void* const* d_in, const int* in_sizes, int n_in,
                              void* d_out, int out_size, void* d_ws, size_t ws_size,
                              hipStream_t stream) {
    const float* label = (const float*)d_in[0];   // (B,3,2) f32
    const float* est   = (const float*)d_in[1];   // (B,6)   f32
    const int*   mix   = (const int*)d_in[2];     // (B,)    i32
    float* out = (float*)d_out;
    float* partials = (float*)d_ws;

    const long long B = (long long)in_sizes[2];
    const int P = (int)(B / 2);  // B = 4194304, even

    stage1_kernel<<<S1_BLOCKS, S1_TPB, 0, stream>>>(label, est, mix, partials, P);
    stage2_kernel<<<1, 256, 0, stream>>>(partials, out, S1_BLOCKS, B);
}

// Round 4
// 225.106 us; speedup vs baseline: 1.0296x; 1.0296x over previous
//
#include <hip/hip_runtime.h>
#include <math.h>

#define RAD2DEG 57.29577951308232f

constexpr int S1_BLOCKS = 1024;   // longer-lived blocks: 8 pairs/thread
constexpr int S1_TPB    = 256;

typedef float f32x4 __attribute__((ext_vector_type(4)));
typedef int   i32x2 __attribute__((ext_vector_type(2)));

// Absolute angular distance in degrees between vectors (ax,ay) and (bx,by).
// == wrap(atan2(ay,ax)*RAD2DEG - atan2(by,bx)*RAD2DEG) from the reference.
__device__ __forceinline__ float angdist_deg(float ax, float ay,
                                             float bx, float by) {
    float dot = ax * bx + ay * by;
    float cr  = fabsf(ay * bx - ax * by);
    float ad  = fabsf(dot);
    float mn  = fminf(cr, ad);
    float mx  = fmaxf(cr, ad);
    float t   = mn * __builtin_amdgcn_rcpf(fmaxf(mx, 1e-37f));
    float s   = t * t;
    // minimax poly for atan(t), t in [0,1]; max err ~2.3e-5 rad (~0.0013 deg)
    float p = fmaf(s, -0.01172120f, 0.05265332f);
    p = fmaf(s, p, -0.11643287f);
    p = fmaf(s, p,  0.19354346f);
    p = fmaf(s, p, -0.33262347f);
    p = fmaf(s, p,  0.99997726f);
    float a = t * p;                                   // [0, pi/4]
    a = (cr > ad)    ? (1.57079632679489662f - a) : a; // [0, pi/2]
    a = (dot < 0.0f) ? (3.14159265358979323f - a) : a; // [0, pi]
    return a * RAD2DEG;
}

__device__ __forceinline__ void per_row(
    float l1x, float l2x, float l1y, float l2y, float l1z, float l2z,
    float e1x, float e1y, float e1z, float e2x, float e2y, float e2z,
    int mw,
    float& sS, float& sM, float& sC0, float& sM1, float& sM2)
{
    float dx, dy, dz;
    dx = e1x - l1x; dy = e1y - l1y; dz = e1z - l1z;
    float d11 = dx*dx + dy*dy + dz*dz;
    dx = e2x - l2x; dy = e2y - l2y; dz = e2z - l2z;
    float d22 = dx*dx + dy*dy + dz*dz;
    dx = e2x - l1x; dy = e2y - l1y; dz = e2z - l1z;
    float d21 = dx*dx + dy*dy + dz*dz;
    dx = e1x - l2x; dy = e1y - l2y; dz = e1z - l2z;
    float d12 = dx*dx + dy*dy + dz*dz;

    sS += d11;

    float mixed = fminf(d11 + d22, d21 + d12) * (1.0f / 3.0f);
    float m = (mw != 0) ? 1.0f : 0.0f;
    sM  += m * mixed;
    sC0 += 1.0f - m;

    float e11 = angdist_deg(l1x, l1y, e1x, e1y);
    float e22 = angdist_deg(l2x, l2y, e2x, e2y);
    float e12 = angdist_deg(l1x, l1y, e2x, e2y);
    float e21 = angdist_deg(l2x, l2y, e1x, e1y);

    bool ud = (e11 + e22) < (e12 + e21);
    sM1 += ud ? e11 : e12;
    sM2 += ud ? e22 : e21;
}

__device__ __forceinline__ void per_pair(
    const f32x4& L0, const f32x4& L1, const f32x4& L2,
    const f32x4& E0, const f32x4& E1, const f32x4& E2,
    const i32x2& mw,
    float& sS, float& sM, float& sC0, float& sM1, float& sM2)
{
    per_row(L0.x, L0.y, L0.z, L0.w, L1.x, L1.y,
            E0.x, E0.y, E0.z, E0.w, E1.x, E1.y,
            mw.x, sS, sM, sC0, sM1, sM2);
    per_row(L1.z, L1.w, L2.x, L2.y, L2.z, L2.w,
            E1.z, E1.w, E2.x, E2.y, E2.z, E2.w,
            mw.y, sS, sM, sC0, sM1, sM2);
}

// Steady-state register double-buffer: load pair k+1 (nontemporal) while
// computing pair k. Static A/B register sets (no runtime-indexed arrays).
// 1024 blocks x 256 thr -> 8 pairs/thread: long-lived blocks amortize
// dispatch ramp; depth-1 prefetch + 4-5 waves/SIMD TLP covers latency.
__global__ __launch_bounds__(S1_TPB) void stage1_kernel(
    const float* __restrict__ label,
    const float* __restrict__ est,
    const int*   __restrict__ mix,
    float* __restrict__ partials,   // [gridDim.x][5]
    int P)                          // number of row-pairs = B/2
{
    const int tid   = threadIdx.x;
    const int wid   = tid >> 6;
    const int lane  = tid & 63;
    const int gsize = gridDim.x * S1_TPB;
    const int g     = blockIdx.x * S1_TPB + tid;

    const f32x4* lab4 = (const f32x4*)label;
    const f32x4* est4 = (const f32x4*)est;
    const i32x2* mix2 = (const i32x2*)mix;

    float sS = 0.f, sM = 0.f, sC0 = 0.f, sM1 = 0.f, sM2 = 0.f;

    f32x4 LA0, LA1, LA2, EA0, EA1, EA2; i32x2 MA;
    f32x4 LB0, LB1, LB2, EB0, EB1, EB2; i32x2 MB;

#define LOADP(L0, L1, L2, E0, E1, E2, M, idx) do {                     \
        const f32x4* lp_ = lab4 + (size_t)(idx) * 3;                   \
        const f32x4* ep_ = est4 + (size_t)(idx) * 3;                   \
        L0 = __builtin_nontemporal_load(lp_ + 0);                      \
        L1 = __builtin_nontemporal_load(lp_ + 1);                      \
        L2 = __builtin_nontemporal_load(lp_ + 2);                      \
        E0 = __builtin_nontemporal_load(ep_ + 0);                      \
        E1 = __builtin_nontemporal_load(ep_ + 1);                      \
        E2 = __builtin_nontemporal_load(ep_ + 2);                      \
        M  = __builtin_nontemporal_load(mix2 + (idx));                 \
    } while (0)

    if (g < P) {
        const int n = (P - 1 - g) / gsize + 1;   // pairs owned by this thread
        int pload = g + gsize;
        LOADP(LA0, LA1, LA2, EA0, EA1, EA2, MA, g);
        int nrem = n - 1;                        // pairs not yet loaded
        while (nrem >= 2) {
            LOADP(LB0, LB1, LB2, EB0, EB1, EB2, MB, pload);
            pload += gsize;
            per_pair(LA0, LA1, LA2, EA0, EA1, EA2, MA,
                     sS, sM, sC0, sM1, sM2);
            LOADP(LA0, LA1, LA2, EA0, EA1, EA2, MA, pload);
            pload += gsize;
            per_pair(LB0, LB1, LB2, EB0, EB1, EB2, MB,
                     sS, sM, sC0, sM1, sM2);
            nrem -= 2;
        }
        if (nrem == 1) {
            LOADP(LB0, LB1, LB2, EB0, EB1, EB2, MB, pload);
            per_pair(LA0, LA1, LA2, EA0, EA1, EA2, MA,
                     sS, sM, sC0, sM1, sM2);
            per_pair(LB0, LB1, LB2, EB0, EB1, EB2, MB,
                     sS, sM, sC0, sM1, sM2);
        } else {
            per_pair(LA0, LA1, LA2, EA0, EA1, EA2, MA,
                     sS, sM, sC0, sM1, sM2);
        }
    }
#undef LOADP

    // wave (64-lane) shuffle reduction
    for (int off = 32; off > 0; off >>= 1) {
        sS  += __shfl_down(sS,  off, 64);
        sM  += __shfl_down(sM,  off, 64);
        sC0 += __shfl_down(sC0, off, 64);
        sM1 += __shfl_down(sM1, off, 64);
        sM2 += __shfl_down(sM2, off, 64);
    }

    __shared__ float red[S1_TPB / 64][5];
    if (lane == 0) {
        red[wid][0] = sS; red[wid][1] = sM; red[wid][2] = sC0;
        red[wid][3] = sM1; red[wid][4] = sM2;
    }
    __syncthreads();
    if (tid == 0) {
        float r0 = 0.f, r1 = 0.f, r2 = 0.f, r3 = 0.f, r4 = 0.f;
        #pragma unroll
        for (int w = 0; w < S1_TPB / 64; ++w) {
            r0 += red[w][0]; r1 += red[w][1]; r2 += red[w][2];
            r3 += red[w][3]; r4 += red[w][4];
        }
        float* out = partials + (size_t)blockIdx.x * 5;
        out[0] = r0; out[1] = r1; out[2] = r2; out[3] = r3; out[4] = r4;
    }
}

__global__ __launch_bounds__(256) void stage2_kernel(
    const float* __restrict__ partials,
    float* __restrict__ out,
    int nblocks,
    long long Btot)
{
    const int tid = threadIdx.x;
    double aS = 0, aM = 0, aC0 = 0, aM1 = 0, aM2 = 0;
    for (int r = tid; r < nblocks; r += 256) {
        const float* row = partials + (size_t)r * 5;
        aS += row[0]; aM += row[1]; aC0 += row[2]; aM1 += row[3]; aM2 += row[4];
    }
    for (int off = 32; off > 0; off >>= 1) {
        aS  += __shfl_down(aS,  off, 64);
        aM  += __shfl_down(aM,  off, 64);
        aC0 += __shfl_down(aC0, off, 64);
        aM1 += __shfl_down(aM1, off, 64);
        aM2 += __shfl_down(aM2, off, 64);
    }
    __shared__ double red[4][5];
    const int wid = tid >> 6, lane = tid & 63;
    if (lane == 0) {
        red[wid][0] = aS; red[wid][1] = aM; red[wid][2] = aC0;
        red[wid][3] = aM1; red[wid][4] = aM2;
    }
    __syncthreads();
    if (tid == 0) {
        double S = 0, M = 0, C0 = 0, M1 = 0, M2 = 0;
        #pragma unroll
        for (int w = 0; w < 4; ++w) {
            S += red[w][0]; M += red[w][1]; C0 += red[w][2];
            M1 += red[w][3]; M2 += red[w][4];
        }
        const double Bd = (double)Btot;
        const double single_loss = S / (3.0 * Bd);
        out[0] = (float)((C0 * single_loss + M) / Bd);
        out[1] = (float)(M1 / Bd);
        out[2] = (float)(M2 / Bd);
    }
}

extern "C" void kernel_launch(void* const* d_in, const int* in_sizes, int n_in,
                              void* d_out, int out_size, void* d_ws, size_t ws_size,
                              hipStream_t stream) {
    const float* label = (const float*)d_in[0];   // (B,3,2) f32
    const float* est   = (const float*)d_in[1];   // (B,6)   f32
    const int*   mix   = (const int*)d_in[2];     // (B,)    i32
    float* out = (float*)d_out;
    float* partials = (float*)d_ws;

    const long long B = (long long)in_sizes[2];
    const int P = (int)(B / 2);  // B = 4194304, even

    stage1_kernel<<<S1_BLOCKS, S1_TPB, 0, stream>>>(label, est, mix, partials, P);
    stage2_kernel<<<1, 256, 0, stream>>>(partials, out, S1_BLOCKS, B);
}